// Round 1
// baseline (968.558 us; speedup 1.0000x reference)
//
#include <hip/hip_runtime.h>

typedef unsigned int  u32;
typedef unsigned short u16;
typedef __bf16 bf16x8 __attribute__((ext_vector_type(8)));
typedef float  f32x4  __attribute__((ext_vector_type(4)));

// ---- output float offsets (return-order concat) ----
#define O1 16777216    // updated_memory [1024,512]
#define O2 17301504    // sq [16384,1024]  (used as S scratch first, overwritten in place)
#define O3 34078720    // sm [16384,1024]
#define O4 50855936    // diversity_loss_updated
#define O5 50855937    // similarity_loss

// ---- ws byte offsets ----
#define WS_QHI   0u
#define WS_QLO   16777216u
#define WS_KHI   33554432u
#define WS_KLO   34603008u
#define WS_KT    35651584u
#define WS_KNORM 36700160u
#define WS_RN    36769792u
#define WS_PMAX  36835328u
#define WS_PSUM  36900864u
#define WS_CMAX  36966400u
#define WS_CSUM  36970496u
#define WS_ARGM  36974592u
#define WS_WGT   37040128u
#define WS_QU    37105664u
#define WS_SCAL  39202816u   // [0]=sim_acc [1]=maxent(bits) [2]=div_acc [3]=diag_acc

__device__ __forceinline__ u16 bf_rne(float f){
  u32 u = __float_as_uint(f);
  u32 r = u + 0x7fffu + ((u >> 16) & 1u);
  return (u16)(r >> 16);
}
__device__ __forceinline__ float bf_f(u16 h){ return __uint_as_float(((u32)h) << 16); }

__device__ __forceinline__ void glds16(const void* g, void* l){
  __builtin_amdgcn_global_load_lds((const __attribute__((address_space(1))) u32*)g,
                                   (__attribute__((address_space(3))) u32*)l, 16, 0, 0);
}

// ---------------- init: zero query_update + scalars ----------------
__global__ void k_init(float* qu, float* scal){
  int i = blockIdx.x*256 + threadIdx.x;
  if (i < 524288) qu[i] = 0.f;
  if (i < 16) scal[i] = 0.f;
}

// ---------------- keys: norm + bf16 hi/lo split ----------------
__global__ __launch_bounds__(64) void k_keys(const float* __restrict__ keys,
    u16* __restrict__ khi, u16* __restrict__ klo, float* __restrict__ knorm){
  int m = blockIdx.x, l = threadIdx.x;
  const float* kr = keys + (size_t)m*512 + l*8;
  float f[8];
  #pragma unroll
  for (int i=0;i<8;i++) f[i] = kr[i];
  float ss = 0.f;
  #pragma unroll
  for (int i=0;i<8;i++) ss += f[i]*f[i];
  for (int o=32;o>0;o>>=1) ss += __shfl_xor(ss,o);
  if (l == 0) knorm[m] = sqrtf(ss);
  u32 hh[4], ll[4];
  #pragma unroll
  for (int i=0;i<4;i++){
    u16 h0 = bf_rne(f[2*i]);   u16 l0 = bf_rne(f[2*i]   - bf_f(h0));
    u16 h1 = bf_rne(f[2*i+1]); u16 l1 = bf_rne(f[2*i+1] - bf_f(h1));
    hh[i] = (u32)h0 | ((u32)h1<<16);
    ll[i] = (u32)l0 | ((u32)l1<<16);
  }
  *(uint4*)&khi[(size_t)m*512 + l*8] = make_uint4(hh[0],hh[1],hh[2],hh[3]);
  *(uint4*)&klo[(size_t)m*512 + l*8] = make_uint4(ll[0],ll[1],ll[2],ll[3]);
}

// ---------------- keysT bf16 [512 x 1024] for concat GEMM ----------------
__global__ __launch_bounds__(256) void k_keysT(const float* __restrict__ keys, u16* __restrict__ kT){
  __shared__ float t2[64*65];
  int m0 = blockIdx.x*64, c0 = blockIdx.y*64;
  int t = threadIdx.x; int j = t & 63; int ig = t >> 6;
  #pragma unroll 4
  for (int ii=0; ii<16; ++ii){
    int i = ig*16 + ii;
    t2[i*65 + j] = keys[(size_t)(m0+i)*512 + c0 + j];
  }
  __syncthreads();
  #pragma unroll 4
  for (int ii=0; ii<16; ++ii){
    int i = ig*16 + ii;
    kT[(size_t)(c0+i)*1024 + m0 + j] = bf_rne(t2[j*65 + i]);
  }
}

// ---------------- maxent ----------------
__global__ __launch_bounds__(256) void k_maxent(const float* __restrict__ ent, float* scal){
  int i = blockIdx.x*512 + threadIdx.x;
  float v = fmaxf(ent[i], ent[i + 256]);
  for (int o=32;o>0;o>>=1) v = fmaxf(v, __shfl_xor(v,o));
  __shared__ float r4[4];
  if ((threadIdx.x & 63) == 0) r4[threadIdx.x>>6] = v;
  __syncthreads();
  if (threadIdx.x == 0){
    float mx = fmaxf(fmaxf(r4[0],r4[1]), fmaxf(r4[2],r4[3]));
    atomicMax((u32*)(scal + 1), __float_as_uint(mx));
  }
}

// ---------------- phase A: normalize query, write out0 lower half, qr hi/lo, row norms ----------------
__global__ __launch_bounds__(256) void k_phaseA(const float* __restrict__ query, float* __restrict__ out0,
    u16* __restrict__ qhi, u16* __restrict__ qlo, float* __restrict__ rn_g){
  __shared__ float tile[64*65];
  __shared__ float red[256];
  __shared__ float sinv[64];
  int bx = blockIdx.x; int b = bx >> 4; int hw0 = (bx & 15)*64;
  int t = threadIdx.x; int hw = t & 63; int cg = t >> 6;
  const float* qb = query + (size_t)b*524288 + hw0 + hw;
  float p = 0.f;
  for (int c = cg; c < 512; c += 4){ float v = qb[(size_t)c*1024]; p += v*v; }
  red[cg*64 + hw] = p;
  __syncthreads();
  if (t < 64){
    float ss = red[t] + red[64+t] + red[128+t] + red[192+t];
    float nrm = sqrtf(ss);
    float inv = 1.0f / fmaxf(nrm, 1e-12f);
    sinv[t] = inv;
    rn_g[b*1024 + hw0 + t] = nrm * inv;
  }
  __syncthreads();
  int nl = t >> 2, cq = t & 3;
  int n = b*1024 + hw0 + nl;
  float invv = sinv[hw];
  for (int cb = 0; cb < 8; ++cb){
    int cbase = cb*64;
    #pragma unroll 4
    for (int i = 0; i < 16; ++i){
      int cl = cg*16 + i;
      int c = cbase + cl;
      float v = query[(size_t)b*524288 + (size_t)c*1024 + hw0 + hw] * invv;
      tile[cl*65 + hw] = v;
      out0[(size_t)b*1048576 + (size_t)c*1024 + hw0 + hw] = v;
    }
    __syncthreads();
    u32 hh[8], ll[8];
    #pragma unroll
    for (int p2 = 0; p2 < 8; ++p2){
      float f0 = tile[(cq*16 + p2*2)*65 + nl];
      float f1 = tile[(cq*16 + p2*2 + 1)*65 + nl];
      u16 h0 = bf_rne(f0); u16 lo0 = bf_rne(f0 - bf_f(h0));
      u16 h1 = bf_rne(f1); u16 lo1 = bf_rne(f1 - bf_f(h1));
      hh[p2] = (u32)h0 | ((u32)h1 << 16);
      ll[p2] = (u32)lo0 | ((u32)lo1 << 16);
    }
    size_t base = (size_t)n*512 + cbase + cq*16;
    *(uint4*)&qhi[base]     = make_uint4(hh[0],hh[1],hh[2],hh[3]);
    *(uint4*)&qhi[base + 8] = make_uint4(hh[4],hh[5],hh[6],hh[7]);
    *(uint4*)&qlo[base]     = make_uint4(ll[0],ll[1],ll[2],ll[3]);
    *(uint4*)&qlo[base + 8] = make_uint4(ll[4],ll[5],ll[6],ll[7]);
    __syncthreads();
  }
}

// ---------------- score GEMM: S = qr @ keys^T, split-bf16 (3 MFMA terms) ----------------
__global__ __launch_bounds__(256) void k_score(const u16* __restrict__ qhi, const u16* __restrict__ qlo,
    const u16* __restrict__ khi, const u16* __restrict__ klo, float* __restrict__ S){
  __shared__ u16 sAh[8192], sAl[8192], sBh[8192], sBl[8192];  // 4 x 16KB = 64KB
  int tid = threadIdx.x;
  int nt = blockIdx.x >> 3, mt = blockIdx.x & 7;
  int nBase = nt*128, mBase = mt*128;
  int wave = tid >> 6, lane = tid & 63;
  int rw = (wave>>1)*64, cw = (wave&1)*64;
  int m16 = lane & 15, q4 = lane >> 4;
  f32x4 acc[4][4] = {};
  int srow = tid >> 3, sg = tid & 7;
  for (int kit = 0; kit < 8; ++kit){
    int k0 = kit*64;
    #pragma unroll
    for (int it = 0; it < 4; ++it){
      int row = it*32 + srow;
      int gsw = (sg ^ (row & 7)) * 8;
      int lo = it*2048 + tid*8;
      glds16(qhi + (size_t)(nBase + row)*512 + k0 + gsw, &sAh[lo]);
      glds16(qlo + (size_t)(nBase + row)*512 + k0 + gsw, &sAl[lo]);
      glds16(khi + (size_t)(mBase + row)*512 + k0 + gsw, &sBh[lo]);
      glds16(klo + (size_t)(mBase + row)*512 + k0 + gsw, &sBl[lo]);
    }
    __syncthreads();
    #pragma unroll
    for (int ks = 0; ks < 2; ++ks){
      bf16x8 a0[4], a1[4], b0[4], b1[4];
      int g = ks*4 + q4;
      #pragma unroll
      for (int i=0;i<4;i++){
        int r = rw + i*16 + m16;
        int off = r*64 + (g ^ (r&7))*8;
        a0[i] = *(const bf16x8*)&sAh[off];
        a1[i] = *(const bf16x8*)&sAl[off];
      }
      #pragma unroll
      for (int j=0;j<4;j++){
        int r = cw + j*16 + m16;
        int off = r*64 + (g ^ (r&7))*8;
        b0[j] = *(const bf16x8*)&sBh[off];
        b1[j] = *(const bf16x8*)&sBl[off];
      }
      #pragma unroll
      for (int i=0;i<4;i++)
        #pragma unroll
        for (int j=0;j<4;j++){
          acc[i][j] = __builtin_amdgcn_mfma_f32_16x16x32_bf16(a0[i], b0[j], acc[i][j], 0,0,0);
          acc[i][j] = __builtin_amdgcn_mfma_f32_16x16x32_bf16(a0[i], b1[j], acc[i][j], 0,0,0);
          acc[i][j] = __builtin_amdgcn_mfma_f32_16x16x32_bf16(a1[i], b0[j], acc[i][j], 0,0,0);
        }
    }
    __syncthreads();
  }
  #pragma unroll
  for (int i=0;i<4;i++){
    int rbase = nBase + rw + i*16 + q4*4;
    #pragma unroll
    for (int j=0;j<4;j++){
      int col = mBase + cw + j*16 + m16;
      #pragma unroll
      for (int r=0;r<4;r++)
        S[(size_t)(rbase + r)*1024 + col] = acc[i][j][r];
    }
  }
}

// ---------------- column stats (online max/sum over N) ----------------
__global__ __launch_bounds__(256) void k_colstat(const float* __restrict__ S,
    float* __restrict__ pmax, float* __restrict__ psum){
  int c = threadIdx.x & 63;
  int col = blockIdx.x*64 + c;
  int rg = threadIdx.x >> 6;
  int row0 = blockIdx.y*1024 + rg*256;
  float m = -3.4e38f, s = 0.f;
  for (int r=0;r<256;r++){
    float v = S[(size_t)(row0+r)*1024 + col];
    if (v > m){ s = s*__expf(m - v) + 1.f; m = v; }
    else s += __expf(v - m);
  }
  __shared__ float lm[256], ls[256];
  lm[rg*64 + c] = m; ls[rg*64 + c] = s;
  __syncthreads();
  if (threadIdx.x < 64){
    int t = threadIdx.x;
    float M = lm[t];
    for (int g2=1; g2<4; ++g2) M = fmaxf(M, lm[g2*64+t]);
    float st = 0.f;
    for (int g2=0; g2<4; ++g2) st += ls[g2*64+t]*__expf(lm[g2*64+t] - M);
    pmax[blockIdx.y*1024 + blockIdx.x*64 + t] = M;
    psum[blockIdx.y*1024 + blockIdx.x*64 + t] = st;
  }
}

__global__ void k_colfin(const float* __restrict__ pmax, const float* __restrict__ psum,
    float* __restrict__ cmax, float* __restrict__ csum){
  int col = blockIdx.x*256 + threadIdx.x;
  float M = -3.4e38f, s = 0.f;
  for (int ch=0; ch<16; ++ch){
    float mi = pmax[ch*1024 + col], si = psum[ch*1024 + col];
    float nm = fmaxf(M, mi);
    s = s*__expf(M - nm) + si*__expf(mi - nm);
    M = nm;
  }
  cmax[col] = M; csum[col] = s;
}

// ---------------- row softmax: sm out, sq in-place over S, argmax/cos/w ----------------
__global__ __launch_bounds__(256) void k_row(float* __restrict__ S, float* __restrict__ sm,
    const float* __restrict__ cmax, const float* __restrict__ csum,
    const float* __restrict__ rn, const float* __restrict__ knorm,
    const float* __restrict__ ent, const float* __restrict__ scal,
    int* __restrict__ argm, float* __restrict__ wgt, float* __restrict__ sim_acc){
  int wave = threadIdx.x >> 6, lane = threadIdx.x & 63;
  int n = blockIdx.x*4 + wave;
  float4 v[4];
  const float4* Sr = (const float4*)(S + (size_t)n*1024);
  #pragma unroll
  for (int j=0;j<4;j++) v[j] = Sr[j*64 + lane];
  float m = -3.4e38f; int gi = 0;
  #pragma unroll
  for (int j=0;j<4;j++){
    int c0 = j*256 + lane*4;
    if (v[j].x > m){ m=v[j].x; gi=c0; }
    if (v[j].y > m){ m=v[j].y; gi=c0+1; }
    if (v[j].z > m){ m=v[j].z; gi=c0+2; }
    if (v[j].w > m){ m=v[j].w; gi=c0+3; }
  }
  for (int o=32;o>0;o>>=1){
    float om = __shfl_xor(m,o); int oi = __shfl_xor(gi,o);
    if (om > m || (om == m && oi < gi)){ m = om; gi = oi; }
  }
  float4 e[4]; float s = 0.f;
  #pragma unroll
  for (int j=0;j<4;j++){
    e[j].x = __expf(v[j].x - m); e[j].y = __expf(v[j].y - m);
    e[j].z = __expf(v[j].z - m); e[j].w = __expf(v[j].w - m);
    s += e[j].x + e[j].y + e[j].z + e[j].w;
  }
  for (int o=32;o>0;o>>=1) s += __shfl_xor(s,o);
  float ri = 1.f/s;
  float4* smr = (float4*)(sm + (size_t)n*1024);
  #pragma unroll
  for (int j=0;j<4;j++){
    float4 t2; t2.x=e[j].x*ri; t2.y=e[j].y*ri; t2.z=e[j].z*ri; t2.w=e[j].w*ri;
    smr[j*64 + lane] = t2;
  }
  float4* sqr = (float4*)(S + (size_t)n*1024);
  #pragma unroll
  for (int j=0;j<4;j++){
    int c0 = j*256 + lane*4;
    float4 cm = *(const float4*)(cmax + c0);
    float4 cs = *(const float4*)(csum + c0);
    float4 q;
    q.x = __expf(v[j].x - cm.x)/cs.x;
    q.y = __expf(v[j].y - cm.y)/cs.y;
    q.z = __expf(v[j].z - cm.z)/cs.z;
    q.w = __expf(v[j].w - cm.w)/cs.w;
    sqr[j*64 + lane] = q;
  }
  if (lane == 0){
    float en = ent[n];
    float cosv = m / fmaxf(rn[n]*knorm[gi], 1e-8f);
    atomicAdd(sim_acc, (1.f - cosv)*en);
    float w = __expf(m - cmax[gi]) * en / scal[1];
    wgt[n] = w; argm[n] = gi;
  }
}

// ---------------- concat GEMM: out0 upper half = (sm @ keys) transposed to BCHW ----------------
__global__ __launch_bounds__(256) void k_concat(const u16* __restrict__ kT, const float* __restrict__ sm,
    float* __restrict__ out0){
  __shared__ u16 sA[8192];       // keysT tile 128x64 (swizzled)
  __shared__ u16 sB[128*72];     // sm tile 128x64 padded
  int tid = threadIdx.x;
  int ct = blockIdx.x & 3, nt = blockIdx.x >> 2;
  int cBase = ct*128, nBase = nt*128;
  int wave = tid>>6, lane = tid&63;
  int rw = (wave>>1)*64, cw = (wave&1)*64;
  int m16 = lane&15, q4 = lane>>4;
  f32x4 acc[4][4] = {};
  int srow = tid>>3, sg = tid&7;
  int nl = tid>>1, half = tid&1;
  for (int kit=0; kit<16; ++kit){
    int k0 = kit*64;
    #pragma unroll
    for (int it=0; it<4; ++it){
      int row = it*32 + srow;
      int gsw = (sg ^ (row & 7)) * 8;
      glds16(kT + (size_t)(cBase + row)*1024 + k0 + gsw, &sA[it*2048 + tid*8]);
    }
    {
      const float* src = sm + (size_t)(nBase + nl)*1024 + k0 + half*32;
      float4 f[8];
      #pragma unroll
      for (int q=0;q<8;q++) f[q] = *(const float4*)(src + q*4);
      u16* dst = &sB[nl*72 + half*32];
      #pragma unroll
      for (int q=0;q<4;q++){
        const float* fp = (const float*)&f[q*2];
        u32 w0 = (u32)bf_rne(fp[0]) | ((u32)bf_rne(fp[1])<<16);
        u32 w1 = (u32)bf_rne(fp[2]) | ((u32)bf_rne(fp[3])<<16);
        u32 w2 = (u32)bf_rne(fp[4]) | ((u32)bf_rne(fp[5])<<16);
        u32 w3 = (u32)bf_rne(fp[6]) | ((u32)bf_rne(fp[7])<<16);
        *(uint4*)(dst + q*8) = make_uint4(w0,w1,w2,w3);
      }
    }
    __syncthreads();
    #pragma unroll
    for (int ks=0; ks<2; ++ks){
      bf16x8 a[4], b[4];
      int g = ks*4 + q4;
      #pragma unroll
      for (int i=0;i<4;i++){
        int r = rw + i*16 + m16;
        a[i] = *(const bf16x8*)&sA[r*64 + (g ^ (r&7))*8];
      }
      #pragma unroll
      for (int j=0;j<4;j++){
        int r = cw + j*16 + m16;
        b[j] = *(const bf16x8*)&sB[r*72 + ks*32 + q4*8];
      }
      #pragma unroll
      for (int i=0;i<4;i++)
        #pragma unroll
        for (int j=0;j<4;j++)
          acc[i][j] = __builtin_amdgcn_mfma_f32_16x16x32_bf16(a[i], b[j], acc[i][j], 0,0,0);
    }
    __syncthreads();
  }
  #pragma unroll
  for (int i=0;i<4;i++){
    int c = cBase + rw + i*16 + q4*4;
    #pragma unroll
    for (int j=0;j<4;j++){
      int n = nBase + cw + j*16 + m16;
      int b2 = n >> 10, hw = n & 1023;
      #pragma unroll
      for (int r=0;r<4;r++)
        out0[(size_t)b2*1048576 + (size_t)(512 + c + r)*1024 + hw] = acc[i][j][r];
    }
  }
}

// ---------------- scatter: query_update[g] += w * qr ----------------
__global__ __launch_bounds__(256) void k_scatter(const u16* __restrict__ qhi, const u16* __restrict__ qlo,
    const int* __restrict__ argm, const float* __restrict__ wgt, float* __restrict__ qu){
  int wave = threadIdx.x >> 6, lane = threadIdx.x & 63;
  int n = blockIdx.x*4 + wave;
  int g = argm[n]; float w = wgt[n];
  size_t base = (size_t)n*512 + lane*8;
  uint4 hh = *(const uint4*)&qhi[base];
  uint4 ll = *(const uint4*)&qlo[base];
  float* dst = qu + (size_t)g*512 + lane*8;
  const u32* hp = (const u32*)&hh; const u32* lp = (const u32*)&ll;
  #pragma unroll
  for (int k2=0;k2<4;k2++){
    u32 h = hp[k2], l2 = lp[k2];
    float f0 = bf_f((u16)(h & 0xffffu)) + bf_f((u16)(l2 & 0xffffu));
    float f1 = bf_f((u16)(h >> 16))     + bf_f((u16)(l2 >> 16));
    atomicAdd(dst + k2*2,     w*f0);
    atomicAdd(dst + k2*2 + 1, w*f1);
  }
}

// ---------------- updated_memory = l2norm(qu + keys); diag accumulation ----------------
__global__ __launch_bounds__(128) void k_fnorm(const float* __restrict__ qu, const float* __restrict__ keys,
    float* __restrict__ out1, float* __restrict__ scal){
  int m = blockIdx.x, t = threadIdx.x;
  int wave = t >> 6, lane = t & 63;
  const float4* a4 = (const float4*)(qu + (size_t)m*512);
  const float4* k4 = (const float4*)(keys + (size_t)m*512);
  float4 a = a4[t], k = k4[t];
  float4 u; u.x=a.x+k.x; u.y=a.y+k.y; u.z=a.z+k.z; u.w=a.w+k.w;
  float ss = u.x*u.x + u.y*u.y + u.z*u.z + u.w*u.w;
  for (int o=32;o>0;o>>=1) ss += __shfl_xor(ss,o);
  __shared__ float r2[2];
  if (lane == 0) r2[wave] = ss;
  __syncthreads();
  float tot = r2[0] + r2[1];
  float inv = 1.f / fmaxf(sqrtf(tot), 1e-12f);
  float4 o4; o4.x=u.x*inv; o4.y=u.y*inv; o4.z=u.z*inv; o4.w=u.w*inv;
  ((float4*)(out1 + (size_t)m*512))[t] = o4;
  if (t == 0){
    float s2 = tot*inv*inv;
    atomicAdd(scal + 3, s2*s2);
  }
}

// ---------------- gram diversity: sum over (c1,c2) of (U^T U)^2 ----------------
__global__ __launch_bounds__(256) void k_gram(const float* __restrict__ U, float* __restrict__ scal){
  __shared__ float Ua[64*34], Ub[64*34];
  int bx = blockIdx.x & 15, by = blockIdx.x >> 4;
  int t = threadIdx.x;
  int c1 = (t >> 4)*2, c2 = (t & 15)*2;
  float d00=0,d01=0,d10=0,d11=0;
  for (int ch=0; ch<16; ++ch){
    #pragma unroll
    for (int j=0;j<8;j++){
      int flat = j*256 + t;
      int ml = flat >> 5, c = flat & 31;
      Ua[ml*34 + c] = U[(size_t)(ch*64 + ml)*512 + bx*32 + c];
      Ub[ml*34 + c] = U[(size_t)(ch*64 + ml)*512 + by*32 + c];
    }
    __syncthreads();
    #pragma unroll 8
    for (int ml=0; ml<64; ++ml){
      float2 a = *(const float2*)&Ua[ml*34 + c1];
      float2 b = *(const float2*)&Ub[ml*34 + c2];
      d00 += a.x*b.x; d01 += a.x*b.y; d10 += a.y*b.x; d11 += a.y*b.y;
    }
    __syncthreads();
  }
  float loc = d00*d00 + d01*d01 + d10*d10 + d11*d11;
  for (int o=32;o>0;o>>=1) loc += __shfl_xor(loc,o);
  __shared__ float r4[4];
  if ((t&63) == 0) r4[t>>6] = loc;
  __syncthreads();
  if (t == 0) atomicAdd(scal + 2, r4[0]+r4[1]+r4[2]+r4[3]);
}

// ---------------- final scalars ----------------
__global__ void k_final(const float* __restrict__ scal, float* __restrict__ out){
  out[O4] = (scal[2] - scal[3]) * (1.0f/1047552.0f);
  out[O5] = scal[0];
}

extern "C" void kernel_launch(void* const* d_in, const int* in_sizes, int n_in,
                              void* d_out, int out_size, void* d_ws, size_t ws_size,
                              hipStream_t stream) {
  const float* query = (const float*)d_in[0];
  const float* keys  = (const float*)d_in[1];
  const float* ent   = (const float*)d_in[2];
  float* out  = (float*)d_out;
  char*  ws   = (char*)d_ws;

  u16*   qhi   = (u16*)(ws + WS_QHI);
  u16*   qlo   = (u16*)(ws + WS_QLO);
  u16*   khi   = (u16*)(ws + WS_KHI);
  u16*   klo   = (u16*)(ws + WS_KLO);
  u16*   kT    = (u16*)(ws + WS_KT);
  float* knorm = (float*)(ws + WS_KNORM);
  float* rn    = (float*)(ws + WS_RN);
  float* pmax  = (float*)(ws + WS_PMAX);
  float* psum  = (float*)(ws + WS_PSUM);
  float* cmax  = (float*)(ws + WS_CMAX);
  float* csum  = (float*)(ws + WS_CSUM);
  int*   argm  = (int*)(ws + WS_ARGM);
  float* wgt   = (float*)(ws + WS_WGT);
  float* qu    = (float*)(ws + WS_QU);
  float* scal  = (float*)(ws + WS_SCAL);

  float* S   = out + O2;   // scratch then sq (overwritten in place by k_row)
  float* sm  = out + O3;
  float* um  = out + O1;

  k_init   <<<2048, 256, 0, stream>>>(qu, scal);
  k_keys   <<<1024,  64, 0, stream>>>(keys, khi, klo, knorm);
  k_keysT  <<<dim3(16,8), 256, 0, stream>>>(keys, kT);
  k_maxent <<<32,   256, 0, stream>>>(ent, scal);
  k_phaseA <<<256,  256, 0, stream>>>(query, out, qhi, qlo, rn);
  k_score  <<<1024, 256, 0, stream>>>(qhi, qlo, khi, klo, S);
  k_colstat<<<dim3(16,16), 256, 0, stream>>>(S, pmax, psum);
  k_colfin <<<4,    256, 0, stream>>>(pmax, psum, cmax, csum);
  k_row    <<<4096, 256, 0, stream>>>(S, sm, cmax, csum, rn, knorm, ent, scal, argm, wgt, scal /*sim at [0]*/);
  k_concat <<<512,  256, 0, stream>>>(kT, sm, out);
  k_scatter<<<4096, 256, 0, stream>>>(qhi, qlo, argm, wgt, qu);
  k_fnorm  <<<1024, 128, 0, stream>>>(qu, keys, um, scal);
  k_gram   <<<256,  256, 0, stream>>>(um, scal);
  k_final  <<<1,      1, 0, stream>>>(scal, out);
}

// Round 2
// 582.950 us; speedup vs baseline: 1.6615x; 1.6615x over previous
//
#include <hip/hip_runtime.h>

typedef unsigned int  u32;
typedef unsigned short u16;
typedef __bf16 bf16x8 __attribute__((ext_vector_type(8)));
typedef float  f32x4  __attribute__((ext_vector_type(4)));

// ---- output float offsets (return-order concat) ----
#define O1 16777216    // updated_memory [1024,512]
#define O2 17301504    // sq [16384,1024]  (used as S scratch first, overwritten in place)
#define O3 34078720    // sm [16384,1024]
#define O4 50855936    // diversity_loss_updated
#define O5 50855937    // similarity_loss

// ---- ws byte offsets ----
#define WS_QHI   0u
#define WS_QLO   16777216u
#define WS_KHI   33554432u
#define WS_KLO   34603008u
#define WS_KT    35651584u
#define WS_KNORM 36700160u
#define WS_CNT   36704256u   // u32[1024]
#define WS_OFFS  36708352u   // u32[1025]
#define WS_CUR   36712704u   // u32[1024]
#define WS_RN    36769792u
#define WS_PMAX  36835328u   // reused as list[16384] after k_colfin
#define WS_PSUM  36900864u
#define WS_CMAX  36966400u
#define WS_CSUM  36970496u
#define WS_ARGM  36974592u
#define WS_WGT   37040128u
#define WS_SCAL  39202816u   // [0]=sim_acc [1]=maxent(bits) [2]=div_acc [3]=diag_acc

__device__ __forceinline__ u16 bf_rne(float f){
  u32 u = __float_as_uint(f);
  u32 r = u + 0x7fffu + ((u >> 16) & 1u);
  return (u16)(r >> 16);
}
__device__ __forceinline__ float bf_f(u16 h){ return __uint_as_float(((u32)h) << 16); }

__device__ __forceinline__ void glds16(const void* g, void* l){
  __builtin_amdgcn_global_load_lds((const __attribute__((address_space(1))) u32*)g,
                                   (__attribute__((address_space(3))) u32*)l, 16, 0, 0);
}

// ---------------- init: zero counters + scalars ----------------
__global__ void k_init(u32* count, float* scal){
  int i = blockIdx.x*256 + threadIdx.x;
  if (i < 1024) count[i] = 0u;
  if (i < 16) scal[i] = 0.f;
}

// ---------------- keys: norm + bf16 hi/lo split ----------------
__global__ __launch_bounds__(64) void k_keys(const float* __restrict__ keys,
    u16* __restrict__ khi, u16* __restrict__ klo, float* __restrict__ knorm){
  int m = blockIdx.x, l = threadIdx.x;
  const float* kr = keys + (size_t)m*512 + l*8;
  float f[8];
  #pragma unroll
  for (int i=0;i<8;i++) f[i] = kr[i];
  float ss = 0.f;
  #pragma unroll
  for (int i=0;i<8;i++) ss += f[i]*f[i];
  for (int o=32;o>0;o>>=1) ss += __shfl_xor(ss,o);
  if (l == 0) knorm[m] = sqrtf(ss);
  u32 hh[4], ll[4];
  #pragma unroll
  for (int i=0;i<4;i++){
    u16 h0 = bf_rne(f[2*i]);   u16 l0 = bf_rne(f[2*i]   - bf_f(h0));
    u16 h1 = bf_rne(f[2*i+1]); u16 l1 = bf_rne(f[2*i+1] - bf_f(h1));
    hh[i] = (u32)h0 | ((u32)h1<<16);
    ll[i] = (u32)l0 | ((u32)l1<<16);
  }
  *(uint4*)&khi[(size_t)m*512 + l*8] = make_uint4(hh[0],hh[1],hh[2],hh[3]);
  *(uint4*)&klo[(size_t)m*512 + l*8] = make_uint4(ll[0],ll[1],ll[2],ll[3]);
}

// ---------------- keysT bf16 [512 x 1024] for concat GEMM ----------------
__global__ __launch_bounds__(256) void k_keysT(const float* __restrict__ keys, u16* __restrict__ kT){
  __shared__ float t2[64*65];
  int m0 = blockIdx.x*64, c0 = blockIdx.y*64;
  int t = threadIdx.x; int j = t & 63; int ig = t >> 6;
  #pragma unroll 4
  for (int ii=0; ii<16; ++ii){
    int i = ig*16 + ii;
    t2[i*65 + j] = keys[(size_t)(m0+i)*512 + c0 + j];
  }
  __syncthreads();
  #pragma unroll 4
  for (int ii=0; ii<16; ++ii){
    int i = ig*16 + ii;
    kT[(size_t)(c0+i)*1024 + m0 + j] = bf_rne(t2[j*65 + i]);
  }
}

// ---------------- maxent ----------------
__global__ __launch_bounds__(256) void k_maxent(const float* __restrict__ ent, float* scal){
  int i = blockIdx.x*512 + threadIdx.x;
  float v = fmaxf(ent[i], ent[i + 256]);
  for (int o=32;o>0;o>>=1) v = fmaxf(v, __shfl_xor(v,o));
  __shared__ float r4[4];
  if ((threadIdx.x & 63) == 0) r4[threadIdx.x>>6] = v;
  __syncthreads();
  if (threadIdx.x == 0){
    float mx = fmaxf(fmaxf(r4[0],r4[1]), fmaxf(r4[2],r4[3]));
    atomicMax((u32*)(scal + 1), __float_as_uint(mx));
  }
}

// ---------------- phase A: normalize query, write out0 lower half, qr hi/lo, row norms ----------------
__global__ __launch_bounds__(256) void k_phaseA(const float* __restrict__ query, float* __restrict__ out0,
    u16* __restrict__ qhi, u16* __restrict__ qlo, float* __restrict__ rn_g){
  __shared__ float tile[64*65];
  __shared__ float red[256];
  __shared__ float sinv[64];
  int bx = blockIdx.x; int b = bx >> 4; int hw0 = (bx & 15)*64;
  int t = threadIdx.x; int hw = t & 63; int cg = t >> 6;
  const float* qb = query + (size_t)b*524288 + hw0 + hw;
  float p = 0.f;
  for (int c = cg; c < 512; c += 4){ float v = qb[(size_t)c*1024]; p += v*v; }
  red[cg*64 + hw] = p;
  __syncthreads();
  if (t < 64){
    float ss = red[t] + red[64+t] + red[128+t] + red[192+t];
    float nrm = sqrtf(ss);
    float inv = 1.0f / fmaxf(nrm, 1e-12f);
    sinv[t] = inv;
    rn_g[b*1024 + hw0 + t] = nrm * inv;
  }
  __syncthreads();
  int nl = t >> 2, cq = t & 3;
  int n = b*1024 + hw0 + nl;
  float invv = sinv[hw];
  for (int cb = 0; cb < 8; ++cb){
    int cbase = cb*64;
    #pragma unroll 4
    for (int i = 0; i < 16; ++i){
      int cl = cg*16 + i;
      int c = cbase + cl;
      float v = query[(size_t)b*524288 + (size_t)c*1024 + hw0 + hw] * invv;
      tile[cl*65 + hw] = v;
      out0[(size_t)b*1048576 + (size_t)c*1024 + hw0 + hw] = v;
    }
    __syncthreads();
    u32 hh[8], ll[8];
    #pragma unroll
    for (int p2 = 0; p2 < 8; ++p2){
      float f0 = tile[(cq*16 + p2*2)*65 + nl];
      float f1 = tile[(cq*16 + p2*2 + 1)*65 + nl];
      u16 h0 = bf_rne(f0); u16 lo0 = bf_rne(f0 - bf_f(h0));
      u16 h1 = bf_rne(f1); u16 lo1 = bf_rne(f1 - bf_f(h1));
      hh[p2] = (u32)h0 | ((u32)h1 << 16);
      ll[p2] = (u32)lo0 | ((u32)lo1 << 16);
    }
    size_t base = (size_t)n*512 + cbase + cq*16;
    *(uint4*)&qhi[base]     = make_uint4(hh[0],hh[1],hh[2],hh[3]);
    *(uint4*)&qhi[base + 8] = make_uint4(hh[4],hh[5],hh[6],hh[7]);
    *(uint4*)&qlo[base]     = make_uint4(ll[0],ll[1],ll[2],ll[3]);
    *(uint4*)&qlo[base + 8] = make_uint4(ll[4],ll[5],ll[6],ll[7]);
    __syncthreads();
  }
}

// ---------------- score GEMM: S = qr @ keys^T, split-bf16 (3 MFMA terms) ----------------
__global__ __launch_bounds__(256) void k_score(const u16* __restrict__ qhi, const u16* __restrict__ qlo,
    const u16* __restrict__ khi, const u16* __restrict__ klo, float* __restrict__ S){
  __shared__ u16 sAh[8192], sAl[8192], sBh[8192], sBl[8192];  // 4 x 16KB = 64KB
  int tid = threadIdx.x;
  int nt = blockIdx.x >> 3, mt = blockIdx.x & 7;
  int nBase = nt*128, mBase = mt*128;
  int wave = tid >> 6, lane = tid & 63;
  int rw = (wave>>1)*64, cw = (wave&1)*64;
  int m16 = lane & 15, q4 = lane >> 4;
  f32x4 acc[4][4] = {};
  int srow = tid >> 3, sg = tid & 7;
  for (int kit = 0; kit < 8; ++kit){
    int k0 = kit*64;
    #pragma unroll
    for (int it = 0; it < 4; ++it){
      int row = it*32 + srow;
      int gsw = (sg ^ (row & 7)) * 8;
      int lo = it*2048 + tid*8;
      glds16(qhi + (size_t)(nBase + row)*512 + k0 + gsw, &sAh[lo]);
      glds16(qlo + (size_t)(nBase + row)*512 + k0 + gsw, &sAl[lo]);
      glds16(khi + (size_t)(mBase + row)*512 + k0 + gsw, &sBh[lo]);
      glds16(klo + (size_t)(mBase + row)*512 + k0 + gsw, &sBl[lo]);
    }
    __syncthreads();
    #pragma unroll
    for (int ks = 0; ks < 2; ++ks){
      bf16x8 a0[4], a1[4], b0[4], b1[4];
      int g = ks*4 + q4;
      #pragma unroll
      for (int i=0;i<4;i++){
        int r = rw + i*16 + m16;
        int off = r*64 + (g ^ (r&7))*8;
        a0[i] = *(const bf16x8*)&sAh[off];
        a1[i] = *(const bf16x8*)&sAl[off];
      }
      #pragma unroll
      for (int j=0;j<4;j++){
        int r = cw + j*16 + m16;
        int off = r*64 + (g ^ (r&7))*8;
        b0[j] = *(const bf16x8*)&sBh[off];
        b1[j] = *(const bf16x8*)&sBl[off];
      }
      #pragma unroll
      for (int i=0;i<4;i++)
        #pragma unroll
        for (int j=0;j<4;j++){
          acc[i][j] = __builtin_amdgcn_mfma_f32_16x16x32_bf16(a0[i], b0[j], acc[i][j], 0,0,0);
          acc[i][j] = __builtin_amdgcn_mfma_f32_16x16x32_bf16(a0[i], b1[j], acc[i][j], 0,0,0);
          acc[i][j] = __builtin_amdgcn_mfma_f32_16x16x32_bf16(a1[i], b0[j], acc[i][j], 0,0,0);
        }
    }
    __syncthreads();
  }
  #pragma unroll
  for (int i=0;i<4;i++){
    int rbase = nBase + rw + i*16 + q4*4;
    #pragma unroll
    for (int j=0;j<4;j++){
      int col = mBase + cw + j*16 + m16;
      #pragma unroll
      for (int r=0;r<4;r++)
        S[(size_t)(rbase + r)*1024 + col] = acc[i][j][r];
    }
  }
}

// ---------------- column stats (online max/sum over N) ----------------
__global__ __launch_bounds__(256) void k_colstat(const float* __restrict__ S,
    float* __restrict__ pmax, float* __restrict__ psum){
  int c = threadIdx.x & 63;
  int col = blockIdx.x*64 + c;
  int rg = threadIdx.x >> 6;
  int row0 = blockIdx.y*1024 + rg*256;
  float m = -3.4e38f, s = 0.f;
  for (int r=0;r<256;r++){
    float v = S[(size_t)(row0+r)*1024 + col];
    if (v > m){ s = s*__expf(m - v) + 1.f; m = v; }
    else s += __expf(v - m);
  }
  __shared__ float lm[256], ls[256];
  lm[rg*64 + c] = m; ls[rg*64 + c] = s;
  __syncthreads();
  if (threadIdx.x < 64){
    int t = threadIdx.x;
    float M = lm[t];
    for (int g2=1; g2<4; ++g2) M = fmaxf(M, lm[g2*64+t]);
    float st = 0.f;
    for (int g2=0; g2<4; ++g2) st += ls[g2*64+t]*__expf(lm[g2*64+t] - M);
    pmax[blockIdx.y*1024 + blockIdx.x*64 + t] = M;
    psum[blockIdx.y*1024 + blockIdx.x*64 + t] = st;
  }
}

__global__ void k_colfin(const float* __restrict__ pmax, const float* __restrict__ psum,
    float* __restrict__ cmax, float* __restrict__ csum){
  int col = blockIdx.x*256 + threadIdx.x;
  float M = -3.4e38f, s = 0.f;
  for (int ch=0; ch<16; ++ch){
    float mi = pmax[ch*1024 + col], si = psum[ch*1024 + col];
    float nm = fmaxf(M, mi);
    s = s*__expf(M - nm) + si*__expf(mi - nm);
    M = nm;
  }
  cmax[col] = M; csum[col] = s;
}

// ---------------- row softmax: sm out, sq in-place over S, argmax/cos/w/count ----------------
__global__ __launch_bounds__(256) void k_row(float* __restrict__ S, float* __restrict__ sm,
    const float* __restrict__ cmax, const float* __restrict__ csum,
    const float* __restrict__ rn, const float* __restrict__ knorm,
    const float* __restrict__ ent, const float* __restrict__ scal,
    int* __restrict__ argm, float* __restrict__ wgt, u32* __restrict__ count,
    float* __restrict__ sim_acc){
  int wave = threadIdx.x >> 6, lane = threadIdx.x & 63;
  int n = blockIdx.x*4 + wave;
  float4 v[4];
  const float4* Sr = (const float4*)(S + (size_t)n*1024);
  #pragma unroll
  for (int j=0;j<4;j++) v[j] = Sr[j*64 + lane];
  float m = -3.4e38f; int gi = 0;
  #pragma unroll
  for (int j=0;j<4;j++){
    int c0 = j*256 + lane*4;
    if (v[j].x > m){ m=v[j].x; gi=c0; }
    if (v[j].y > m){ m=v[j].y; gi=c0+1; }
    if (v[j].z > m){ m=v[j].z; gi=c0+2; }
    if (v[j].w > m){ m=v[j].w; gi=c0+3; }
  }
  for (int o=32;o>0;o>>=1){
    float om = __shfl_xor(m,o); int oi = __shfl_xor(gi,o);
    if (om > m || (om == m && oi < gi)){ m = om; gi = oi; }
  }
  float4 e[4]; float s = 0.f;
  #pragma unroll
  for (int j=0;j<4;j++){
    e[j].x = __expf(v[j].x - m); e[j].y = __expf(v[j].y - m);
    e[j].z = __expf(v[j].z - m); e[j].w = __expf(v[j].w - m);
    s += e[j].x + e[j].y + e[j].z + e[j].w;
  }
  for (int o=32;o>0;o>>=1) s += __shfl_xor(s,o);
  float ri = 1.f/s;
  float4* smr = (float4*)(sm + (size_t)n*1024);
  #pragma unroll
  for (int j=0;j<4;j++){
    float4 t2; t2.x=e[j].x*ri; t2.y=e[j].y*ri; t2.z=e[j].z*ri; t2.w=e[j].w*ri;
    smr[j*64 + lane] = t2;
  }
  float4* sqr = (float4*)(S + (size_t)n*1024);
  #pragma unroll
  for (int j=0;j<4;j++){
    int c0 = j*256 + lane*4;
    float4 cm = *(const float4*)(cmax + c0);
    float4 cs = *(const float4*)(csum + c0);
    float4 q;
    q.x = __expf(v[j].x - cm.x)/cs.x;
    q.y = __expf(v[j].y - cm.y)/cs.y;
    q.z = __expf(v[j].z - cm.z)/cs.z;
    q.w = __expf(v[j].w - cm.w)/cs.w;
    sqr[j*64 + lane] = q;
  }
  __shared__ float simw[4];
  if (lane == 0){
    float en = ent[n];
    float cosv = m / fmaxf(rn[n]*knorm[gi], 1e-8f);
    simw[wave] = (1.f - cosv)*en;
    float w = __expf(m - cmax[gi]) * en / scal[1];
    wgt[n] = w; argm[n] = gi;
    atomicAdd(&count[gi], 1u);
  }
  __syncthreads();
  if (threadIdx.x == 0)
    atomicAdd(sim_acc, simw[0]+simw[1]+simw[2]+simw[3]);
}

// ---------------- exclusive scan of 1024 counts -> offs + cursor ----------------
__global__ __launch_bounds__(256) void k_scan(const u32* __restrict__ count,
    u32* __restrict__ offs, u32* __restrict__ cursor){
  int t = threadIdx.x;
  u32 v0 = count[t*4], v1 = count[t*4+1], v2 = count[t*4+2], v3 = count[t*4+3];
  u32 s = v0+v1+v2+v3;
  u32 x = s;
  for (int o=1;o<64;o<<=1){ u32 y = __shfl_up(x,o); if ((t&63) >= o) x += y; }
  __shared__ u32 wsum[4];
  if ((t&63) == 63) wsum[t>>6] = x;
  __syncthreads();
  u32 wb = 0;
  for (int wv=0; wv < (t>>6); ++wv) wb += wsum[wv];
  u32 excl = wb + x - s;
  u32 o0 = excl, o1 = excl+v0, o2 = excl+v0+v1, o3 = excl+v0+v1+v2;
  offs[t*4]=o0; offs[t*4+1]=o1; offs[t*4+2]=o2; offs[t*4+3]=o3;
  cursor[t*4]=o0; cursor[t*4+1]=o1; cursor[t*4+2]=o2; cursor[t*4+3]=o3;
  if (t == 255) offs[1024] = 16384u;
}

// ---------------- bucket fill ----------------
__global__ __launch_bounds__(256) void k_bucket(const int* __restrict__ argm,
    u32* __restrict__ cursor, u32* __restrict__ list){
  int n = blockIdx.x*256 + threadIdx.x;
  int g = argm[n];
  u32 pos = atomicAdd(&cursor[g], 1u);
  list[pos] = n;
}

// ---------------- gather segment-sum + fused fnorm: out1 = l2norm(sum + keys) ----------------
__global__ __launch_bounds__(128) void k_gather(const u16* __restrict__ qhi, const u16* __restrict__ qlo,
    const u32* __restrict__ offs, const u32* __restrict__ list, const float* __restrict__ wgt,
    const float* __restrict__ keys, float* __restrict__ out1, float* __restrict__ scal){
  int m = blockIdx.x, t = threadIdx.x;
  int c0 = t*4;
  float a0=0.f,a1=0.f,a2=0.f,a3=0.f;
  u32 beg = offs[m], end = offs[m+1];
  for (u32 r = beg; r < end; ++r){
    int n = (int)list[r];
    float w = wgt[n];
    uint2 hh = *(const uint2*)&qhi[(size_t)n*512 + c0];
    uint2 ll = *(const uint2*)&qlo[(size_t)n*512 + c0];
    float f0 = bf_f((u16)(hh.x & 0xffffu)) + bf_f((u16)(ll.x & 0xffffu));
    float f1 = bf_f((u16)(hh.x >> 16))     + bf_f((u16)(ll.x >> 16));
    float f2 = bf_f((u16)(hh.y & 0xffffu)) + bf_f((u16)(ll.y & 0xffffu));
    float f3 = bf_f((u16)(hh.y >> 16))     + bf_f((u16)(ll.y >> 16));
    a0 += w*f0; a1 += w*f1; a2 += w*f2; a3 += w*f3;
  }
  float4 k4 = *(const float4*)(keys + (size_t)m*512 + c0);
  float u0 = a0 + k4.x, u1 = a1 + k4.y, u2 = a2 + k4.z, u3 = a3 + k4.w;
  float ss = u0*u0 + u1*u1 + u2*u2 + u3*u3;
  for (int o=32;o>0;o>>=1) ss += __shfl_xor(ss,o);
  __shared__ float r2[2];
  if ((t&63) == 0) r2[t>>6] = ss;
  __syncthreads();
  float tot = r2[0] + r2[1];
  float inv = 1.f / fmaxf(sqrtf(tot), 1e-12f);
  float4 o4; o4.x=u0*inv; o4.y=u1*inv; o4.z=u2*inv; o4.w=u3*inv;
  *(float4*)(out1 + (size_t)m*512 + c0) = o4;
  if (t == 0){
    float s2 = tot*inv*inv;
    atomicAdd(scal + 3, s2*s2);
  }
}

// ---------------- concat GEMM: out0 upper half = (sm @ keys) transposed to BCHW ----------------
__global__ __launch_bounds__(256) void k_concat(const u16* __restrict__ kT, const float* __restrict__ sm,
    float* __restrict__ out0){
  __shared__ u16 sA[8192];       // keysT tile 128x64 (swizzled)
  __shared__ u16 sB[128*72];     // sm tile 128x64 padded
  int tid = threadIdx.x;
  int ct = blockIdx.x & 3, nt = blockIdx.x >> 2;
  int cBase = ct*128, nBase = nt*128;
  int wave = tid>>6, lane = tid&63;
  int rw = (wave>>1)*64, cw = (wave&1)*64;
  int m16 = lane&15, q4 = lane>>4;
  f32x4 acc[4][4] = {};
  int srow = tid>>3, sg = tid&7;
  int nl = tid>>1, half = tid&1;
  for (int kit=0; kit<16; ++kit){
    int k0 = kit*64;
    #pragma unroll
    for (int it=0; it<4; ++it){
      int row = it*32 + srow;
      int gsw = (sg ^ (row & 7)) * 8;
      glds16(kT + (size_t)(cBase + row)*1024 + k0 + gsw, &sA[it*2048 + tid*8]);
    }
    {
      const float* src = sm + (size_t)(nBase + nl)*1024 + k0 + half*32;
      float4 f[8];
      #pragma unroll
      for (int q=0;q<8;q++) f[q] = *(const float4*)(src + q*4);
      u16* dst = &sB[nl*72 + half*32];
      #pragma unroll
      for (int q=0;q<4;q++){
        const float* fp = (const float*)&f[q*2];
        u32 w0 = (u32)bf_rne(fp[0]) | ((u32)bf_rne(fp[1])<<16);
        u32 w1 = (u32)bf_rne(fp[2]) | ((u32)bf_rne(fp[3])<<16);
        u32 w2 = (u32)bf_rne(fp[4]) | ((u32)bf_rne(fp[5])<<16);
        u32 w3 = (u32)bf_rne(fp[6]) | ((u32)bf_rne(fp[7])<<16);
        *(uint4*)(dst + q*8) = make_uint4(w0,w1,w2,w3);
      }
    }
    __syncthreads();
    #pragma unroll
    for (int ks=0; ks<2; ++ks){
      bf16x8 a[4], b[4];
      int g = ks*4 + q4;
      #pragma unroll
      for (int i=0;i<4;i++){
        int r = rw + i*16 + m16;
        a[i] = *(const bf16x8*)&sA[r*64 + (g ^ (r&7))*8];
      }
      #pragma unroll
      for (int j=0;j<4;j++){
        int r = cw + j*16 + m16;
        b[j] = *(const bf16x8*)&sB[r*72 + ks*32 + q4*8];
      }
      #pragma unroll
      for (int i=0;i<4;i++)
        #pragma unroll
        for (int j=0;j<4;j++)
          acc[i][j] = __builtin_amdgcn_mfma_f32_16x16x32_bf16(a[i], b[j], acc[i][j], 0,0,0);
    }
    __syncthreads();
  }
  #pragma unroll
  for (int i=0;i<4;i++){
    int c = cBase + rw + i*16 + q4*4;
    #pragma unroll
    for (int j=0;j<4;j++){
      int n = nBase + cw + j*16 + m16;
      int b2 = n >> 10, hw = n & 1023;
      #pragma unroll
      for (int r=0;r<4;r++)
        out0[(size_t)b2*1048576 + (size_t)(512 + c + r)*1024 + hw] = acc[i][j][r];
    }
  }
}

// ---------------- gram diversity: sum over (c1,c2) of (U^T U)^2 ----------------
__global__ __launch_bounds__(256) void k_gram(const float* __restrict__ U, float* __restrict__ scal){
  __shared__ float Ua[64*34], Ub[64*34];
  int bx = blockIdx.x & 15, by = blockIdx.x >> 4;
  int t = threadIdx.x;
  int c1 = (t >> 4)*2, c2 = (t & 15)*2;
  float d00=0,d01=0,d10=0,d11=0;
  for (int ch=0; ch<16; ++ch){
    #pragma unroll
    for (int j=0;j<8;j++){
      int flat = j*256 + t;
      int ml = flat >> 5, c = flat & 31;
      Ua[ml*34 + c] = U[(size_t)(ch*64 + ml)*512 + bx*32 + c];
      Ub[ml*34 + c] = U[(size_t)(ch*64 + ml)*512 + by*32 + c];
    }
    __syncthreads();
    #pragma unroll 8
    for (int ml=0; ml<64; ++ml){
      float2 a = *(const float2*)&Ua[ml*34 + c1];
      float2 b = *(const float2*)&Ub[ml*34 + c2];
      d00 += a.x*b.x; d01 += a.x*b.y; d10 += a.y*b.x; d11 += a.y*b.y;
    }
    __syncthreads();
  }
  float loc = d00*d00 + d01*d01 + d10*d10 + d11*d11;
  for (int o=32;o>0;o>>=1) loc += __shfl_xor(loc,o);
  __shared__ float r4[4];
  if ((t&63) == 0) r4[t>>6] = loc;
  __syncthreads();
  if (t == 0) atomicAdd(scal + 2, r4[0]+r4[1]+r4[2]+r4[3]);
}

// ---------------- final scalars ----------------
__global__ void k_final(const float* __restrict__ scal, float* __restrict__ out){
  out[O4] = (scal[2] - scal[3]) * (1.0f/1047552.0f);
  out[O5] = scal[0];
}

extern "C" void kernel_launch(void* const* d_in, const int* in_sizes, int n_in,
                              void* d_out, int out_size, void* d_ws, size_t ws_size,
                              hipStream_t stream) {
  const float* query = (const float*)d_in[0];
  const float* keys  = (const float*)d_in[1];
  const float* ent   = (const float*)d_in[2];
  float* out  = (float*)d_out;
  char*  ws   = (char*)d_ws;

  u16*   qhi   = (u16*)(ws + WS_QHI);
  u16*   qlo   = (u16*)(ws + WS_QLO);
  u16*   khi   = (u16*)(ws + WS_KHI);
  u16*   klo   = (u16*)(ws + WS_KLO);
  u16*   kT    = (u16*)(ws + WS_KT);
  float* knorm = (float*)(ws + WS_KNORM);
  u32*   count = (u32*)(ws + WS_CNT);
  u32*   offs  = (u32*)(ws + WS_OFFS);
  u32*   cursor= (u32*)(ws + WS_CUR);
  float* rn    = (float*)(ws + WS_RN);
  float* pmax  = (float*)(ws + WS_PMAX);
  float* psum  = (float*)(ws + WS_PSUM);
  float* cmax  = (float*)(ws + WS_CMAX);
  float* csum  = (float*)(ws + WS_CSUM);
  int*   argm  = (int*)(ws + WS_ARGM);
  float* wgt   = (float*)(ws + WS_WGT);
  float* scal  = (float*)(ws + WS_SCAL);
  u32*   list  = (u32*)(ws + WS_PMAX);   // reuse pmax after k_colfin

  float* S   = out + O2;   // scratch then sq (overwritten in place by k_row)
  float* sm  = out + O3;
  float* um  = out + O1;

  k_init   <<<4,    256, 0, stream>>>(count, scal);
  k_keys   <<<1024,  64, 0, stream>>>(keys, khi, klo, knorm);
  k_keysT  <<<dim3(16,8), 256, 0, stream>>>(keys, kT);
  k_maxent <<<32,   256, 0, stream>>>(ent, scal);
  k_phaseA <<<256,  256, 0, stream>>>(query, out, qhi, qlo, rn);
  k_score  <<<1024, 256, 0, stream>>>(qhi, qlo, khi, klo, S);
  k_colstat<<<dim3(16,16), 256, 0, stream>>>(S, pmax, psum);
  k_colfin <<<4,    256, 0, stream>>>(pmax, psum, cmax, csum);
  k_row    <<<4096, 256, 0, stream>>>(S, sm, cmax, csum, rn, knorm, ent, scal, argm, wgt, count, scal /*sim at [0]*/);
  k_scan   <<<1,    256, 0, stream>>>(count, offs, cursor);
  k_bucket <<<64,   256, 0, stream>>>(argm, cursor, list);
  k_gather <<<1024, 128, 0, stream>>>(qhi, qlo, offs, list, wgt, keys, um, scal);
  k_concat <<<512,  256, 0, stream>>>(kT, sm, out);
  k_gram   <<<256,  256, 0, stream>>>(um, scal);
  k_final  <<<1,      1, 0, stream>>>(scal, out);
}